// Round 2
// baseline (362.922 us; speedup 1.0000x reference)
//
#include <hip/hip_runtime.h>
#include <hip/hip_bf16.h>
#include <stdint.h>

#define NB 8
#define NSQ 1024
#define NSK 1024
#define NHID 512
#define NHEAD 4
#define NDH 128

typedef __attribute__((ext_vector_type(8))) short short8;
typedef __attribute__((ext_vector_type(4))) float f32x4;

__device__ __forceinline__ unsigned short f2b(float f) {
  unsigned int u = __builtin_bit_cast(unsigned int, f);
  u = u + 0x7FFFu + ((u >> 16) & 1u);
  return (unsigned short)(u >> 16);
}

// ---------------- K0: f32 -> bf16 convert (vectorized, 8 elems/thread) ----
__global__ void cvt_kernel(const float* __restrict__ src,
                           unsigned short* __restrict__ dst, int n) {
  int i = (blockIdx.x * blockDim.x + threadIdx.x) * 8;
  if (i >= n) return;
  float4 a = *(const float4*)(src + i);
  float4 b = *(const float4*)(src + i + 4);
  short8 o;
  o[0] = (short)f2b(a.x); o[1] = (short)f2b(a.y);
  o[2] = (short)f2b(a.z); o[3] = (short)f2b(a.w);
  o[4] = (short)f2b(b.x); o[5] = (short)f2b(b.y);
  o[6] = (short)f2b(b.z); o[7] = (short)f2b(b.w);
  *(short8*)(dst + i) = o;
}

// ---------------- K1: C[m,n] = sum_k A[m,k]*W[n,k]  (both bf16 row-major, K=512)
// MODE 0: C[m*512+n] bf16.  MODE 1: C transposed per-batch: C[((m>>10)*512+n)*1024 + (m&1023)]
template <int MODE>
__global__ __launch_bounds__(256) void gemm_bt(const unsigned short* __restrict__ A,
                                               const unsigned short* __restrict__ W,
                                               unsigned short* __restrict__ C) {
  __shared__ unsigned short tA[128 * 64];  // 128 rows x 64 k (128B rows, XOR-swizzled)
  __shared__ unsigned short tB[128 * 64];
  const int tid = threadIdx.x;
  const int lane = tid & 63;
  const int wave = tid >> 6;
  const int m0 = blockIdx.x * 128;
  const int n0 = blockIdx.y * 128;
  const int wm = (wave & 1) * 64;
  const int wn = (wave >> 1) * 64;
  const int r15 = lane & 15, hi = lane >> 4;

  f32x4 acc[4][4];
  for (int i = 0; i < 4; ++i)
    for (int j = 0; j < 4; ++j) acc[i][j] = (f32x4){0.f, 0.f, 0.f, 0.f};

  for (int kt = 0; kt < 8; ++kt) {
    const int k0 = kt * 64;
    for (int it = 0; it < 4; ++it) {
      int idx = it * 256 + tid;
      int row = idx >> 3, c = idx & 7;
      int cs = c ^ (row & 7);
      short8 va = *(const short8*)(A + (size_t)(m0 + row) * 512 + k0 + c * 8);
      *(short8*)&tA[row * 64 + cs * 8] = va;
      short8 vb = *(const short8*)(W + (size_t)(n0 + row) * 512 + k0 + c * 8);
      *(short8*)&tB[row * 64 + cs * 8] = vb;
    }
    __syncthreads();
    short8 af[2][4], bf[2][4];
    for (int kk = 0; kk < 2; ++kk) {
      for (int mi = 0; mi < 4; ++mi) {
        int row = wm + mi * 16 + r15;
        int ch = kk * 4 + hi;
        af[kk][mi] = *(short8*)&tA[row * 64 + (ch ^ (row & 7)) * 8];
      }
      for (int ni = 0; ni < 4; ++ni) {
        int row = wn + ni * 16 + r15;
        int ch = kk * 4 + hi;
        bf[kk][ni] = *(short8*)&tB[row * 64 + (ch ^ (row & 7)) * 8];
      }
      for (int mi = 0; mi < 4; ++mi)
        for (int ni = 0; ni < 4; ++ni)
          acc[mi][ni] = __builtin_amdgcn_mfma_f32_16x16x32_bf16(
              af[kk][mi], bf[kk][ni], acc[mi][ni], 0, 0, 0);
    }
    __syncthreads();
  }
  for (int mi = 0; mi < 4; ++mi) {
    for (int ni = 0; ni < 4; ++ni) {
      for (int r = 0; r < 4; ++r) {
        int m = m0 + wm + mi * 16 + hi * 4 + r;
        int n = n0 + wn + ni * 16 + r15;
        unsigned short v = f2b(acc[mi][ni][r]);
        if (MODE == 0) {
          C[(size_t)m * 512 + n] = v;
        } else {
          C[((size_t)(m >> 10) * 512 + n) * 1024 + (size_t)(m & 1023)] = v;
        }
      }
    }
  }
}

// ---------------- K2: fused scores+softmax+attn-write+PV -> outh (per-head f32)
__global__ __launch_bounds__(512) void attn_pv_kernel(
    const unsigned short* __restrict__ Qp, const unsigned short* __restrict__ Kp,
    const unsigned short* __restrict__ Vt, const int* __restrict__ mask,
    const float* __restrict__ qmask, float* __restrict__ attn,
    float* __restrict__ outh) {
  __shared__ unsigned short tQ[16 * 128];    // 4KB, swizzled
  __shared__ unsigned short Plds[16 * 1024]; // 32KB bf16 P, swizzled
  __shared__ float outbuf[16][132];          // 8.4KB padded PV reduce buffer
  __shared__ float redmax[16][8];
  __shared__ float redsum[16][8];
  const int qt = blockIdx.x, h = blockIdx.y, b = blockIdx.z;
  const int q0 = qt * 16;
  const int tid = threadIdx.x;
  const int lane = tid & 63, wave = tid >> 6;
  const int r15 = lane & 15, hi = lane >> 4;
  const int kbase = wave * 128;

  // stage Q + zero PV reduce buffer
  if (tid < 256) {
    int row = tid >> 4, c = tid & 15;
    short8 v = *(const short8*)(Qp + (size_t)(b * NSQ + q0 + row) * NHID + h * NDH + c * 8);
    int cs = c ^ (row & 7);
    *(short8*)&tQ[row * 128 + cs * 8] = v;
  }
  for (int i = tid; i < 16 * 132; i += 512) ((float*)outbuf)[i] = 0.f;
  __syncthreads();

  short8 aq[4];
  for (int ks = 0; ks < 4; ++ks) {
    int ch = ks * 4 + hi;
    aq[ks] = *(short8*)&tQ[r15 * 128 + ((ch ^ (r15 & 7)) * 8)];
  }

  // ---- QK^T: wave owns k-columns [kbase, kbase+128) for all 16 q rows ----
  f32x4 acc[8];
  for (int f = 0; f < 8; ++f) acc[f] = (f32x4){0.f, 0.f, 0.f, 0.f};
  const unsigned short* kb = Kp + (size_t)b * NSK * NHID + h * NDH + hi * 8;
  for (int f = 0; f < 8; ++f) {
    const unsigned short* kptr = kb + (size_t)(kbase + f * 16 + r15) * NHID;
    for (int ks = 0; ks < 4; ++ks) {
      short8 bk = *(const short8*)(kptr + ks * 32);
      acc[f] = __builtin_amdgcn_mfma_f32_16x16x32_bf16(aq[ks], bk, acc[f], 0, 0, 0);
    }
  }

  // ---- mask + scale (in registers); acc[f][r] is S[q=hi*4+r][k=kbase+f*16+r15]
  const float isd = 0.08838834764831845f;
  const int* mbase = mask + ((size_t)(b * NSQ) + q0 + hi * 4) * NSK + kbase + r15;
  for (int f = 0; f < 8; ++f)
    for (int r = 0; r < 4; ++r) {
      int mv = mbase[(r << 10) + f * 16];
      float s = acc[f][r] * isd;
      acc[f][r] = mv ? -4294967296.0f : s;
    }

  // ---- row max: local over f, shuffle over r15 group, LDS across waves ----
  float M[4];
  for (int r = 0; r < 4; ++r) {
    float m = acc[0][r];
    for (int f = 1; f < 8; ++f) m = fmaxf(m, acc[f][r]);
    m = fmaxf(m, __shfl_xor(m, 1));
    m = fmaxf(m, __shfl_xor(m, 2));
    m = fmaxf(m, __shfl_xor(m, 4));
    m = fmaxf(m, __shfl_xor(m, 8));
    if (r15 == 0) redmax[hi * 4 + r][wave] = m;
  }
  __syncthreads();
  for (int r = 0; r < 4; ++r) {
    float4 a = *(float4*)&redmax[hi * 4 + r][0];
    float4 c = *(float4*)&redmax[hi * 4 + r][4];
    M[r] = fmaxf(fmaxf(fmaxf(a.x, a.y), fmaxf(a.z, a.w)),
                 fmaxf(fmaxf(c.x, c.y), fmaxf(c.z, c.w)));
  }

  // ---- exp + row sum ----
  for (int r = 0; r < 4; ++r) {
    float sm = 0.f;
    for (int f = 0; f < 8; ++f) {
      float e = __expf(acc[f][r] - M[r]);
      acc[f][r] = e;
      sm += e;
    }
    sm += __shfl_xor(sm, 1);
    sm += __shfl_xor(sm, 2);
    sm += __shfl_xor(sm, 4);
    sm += __shfl_xor(sm, 8);
    if (r15 == 0) redsum[hi * 4 + r][wave] = sm;
  }
  __syncthreads();
  float scl[4];
  for (int r = 0; r < 4; ++r) {
    float4 a = *(float4*)&redsum[hi * 4 + r][0];
    float4 c = *(float4*)&redsum[hi * 4 + r][4];
    float sum = (a.x + a.y + a.z + a.w) + (c.x + c.y + c.z + c.w);
    scl[r] = qmask[b * NSQ + q0 + hi * 4 + r] / sum;
  }

  // ---- write attn f32 + stage P bf16 into swizzled LDS ----
  float* abase = attn + ((size_t)(h * NB + b) * NSQ + q0 + hi * 4) * NSK + kbase + r15;
  for (int f = 0; f < 8; ++f)
    for (int r = 0; r < 4; ++r) {
      float p = acc[f][r] * scl[r];
      abase[(r << 10) + f * 16] = p;
      int q = hi * 4 + r;
      int k = kbase + f * 16 + r15;
      int cw = (k >> 3) ^ (q & 7);
      Plds[q * 1024 + cw * 8 + (k & 7)] = f2b(p);
    }
  // wave reads back only its own columns -> no barrier needed (lgkmcnt only)

  // ---- PV: out_partial[q][d] = sum over this wave's 128 k ----
  f32x4 pacc[8];
  for (int f = 0; f < 8; ++f) pacc[f] = (f32x4){0.f, 0.f, 0.f, 0.f};
  const unsigned short* vb0 =
      Vt + (size_t)(b * NHID + h * NDH + r15) * NSK + kbase + hi * 8;
  for (int kw = 0; kw < 4; ++kw) {
    int kchunk = (kbase >> 3) + kw * 4 + hi;
    short8 pa = *(short8*)&Plds[r15 * 1024 + ((kchunk ^ (r15 & 7)) << 3)];
    for (int f = 0; f < 8; ++f) {
      short8 bv = *(const short8*)(vb0 + (size_t)(f * 16) * NSK + kw * 32);
      pacc[f] = __builtin_amdgcn_mfma_f32_16x16x32_bf16(pa, bv, pacc[f], 0, 0, 0);
    }
  }
  for (int f = 0; f < 8; ++f)
    for (int r = 0; r < 4; ++r)
      atomicAdd(&outbuf[hi * 4 + r][f * 16 + r15], pacc[f][r]);
  __syncthreads();

  // ---- write per-head output ----
  {
    int q = tid >> 5, d0 = (tid & 31) * 4;
    float4 v = *(float4*)&outbuf[q][d0];
    *(float4*)(outh + ((size_t)(b * NSQ) + q0 + q) * NHID + h * NDH + d0) = v;
  }
}

// ---------------- K3: residual + LayerNorm: result = LN(outh + dec) ----------
__global__ __launch_bounds__(256) void ln_kernel(const float* __restrict__ outh,
                                                 const float* __restrict__ dec,
                                                 const float* __restrict__ gamma,
                                                 const float* __restrict__ beta,
                                                 float* __restrict__ result) {
  const int tid = threadIdx.x;
  const int lane = tid & 63, wave = tid >> 6;
  const size_t row = (size_t)blockIdx.x * 4 + wave;
  const float* xr = outh + row * NHID;
  const float* dr = dec + row * NHID;
  float v[8];
  float s = 0.f;
  for (int j = 0; j < 2; ++j) {
    float4 a = *(const float4*)(xr + lane * 8 + j * 4);
    float4 d = *(const float4*)(dr + lane * 8 + j * 4);
    v[j * 4 + 0] = a.x + d.x; v[j * 4 + 1] = a.y + d.y;
    v[j * 4 + 2] = a.z + d.z; v[j * 4 + 3] = a.w + d.w;
  }
  for (int j = 0; j < 8; ++j) s += v[j];
  for (int off = 32; off > 0; off >>= 1) s += __shfl_xor(s, off);
  float mu = s * (1.f / 512.f);
  float s2 = 0.f;
  for (int j = 0; j < 8; ++j) {
    float d = v[j] - mu;
    s2 += d * d;
  }
  for (int off = 32; off > 0; off >>= 1) s2 += __shfl_xor(s2, off);
  float rstd = rsqrtf(s2 * (1.f / 512.f) + 1e-5f);
  float* out = result + row * NHID;
  for (int j = 0; j < 8; ++j) {
    int c = lane * 8 + (j & 3) + (j >> 2) * 4;
    (void)c;
  }
  for (int j = 0; j < 2; ++j) {
    float4 g = *(const float4*)(gamma + lane * 8 + j * 4);
    float4 bt = *(const float4*)(beta + lane * 8 + j * 4);
    float4 o;
    o.x = (v[j * 4 + 0] - mu) * rstd * g.x + bt.x;
    o.y = (v[j * 4 + 1] - mu) * rstd * g.y + bt.y;
    o.z = (v[j * 4 + 2] - mu) * rstd * g.z + bt.z;
    o.w = (v[j * 4 + 3] - mu) * rstd * g.w + bt.w;
    *(float4*)(out + lane * 8 + j * 4) = o;
  }
}

extern "C" void kernel_launch(void* const* d_in, const int* in_sizes, int n_in,
                              void* d_out, int out_size, void* d_ws, size_t ws_size,
                              hipStream_t stream) {
  const float* memory = (const float*)d_in[0];
  const float* dec = (const float*)d_in[1];
  const int* mask = (const int*)d_in[2];
  const float* qmask = (const float*)d_in[3];
  const float* Wk = (const float*)d_in[4];
  const float* Wv = (const float*)d_in[5];
  const float* Wq = (const float*)d_in[6];
  const float* gamma = (const float*)d_in[7];
  const float* beta = (const float*)d_in[8];

  char* ws = (char*)d_ws;
  unsigned short* memB = (unsigned short*)(ws + 0);         // 8  MB
  unsigned short* decB = (unsigned short*)(ws + 8388608);   // 8  MB
  unsigned short* WkB = (unsigned short*)(ws + 16777216);   // .5 MB
  unsigned short* WvB = (unsigned short*)(ws + 17301504);   // .5 MB
  unsigned short* WqB = (unsigned short*)(ws + 17825792);   // .5 MB
  unsigned short* Kp = (unsigned short*)(ws + 18350080);    // 8  MB  [b,s,o]
  unsigned short* Qp = (unsigned short*)(ws + 26738688);    // 8  MB  [b,s,o]
  unsigned short* Vt = (unsigned short*)(ws + 35127296);    // 8  MB  [b,o,s]
  float* outh = (float*)(ws + 0);  // 16 MB, overlays memB/decB (dead after gemms)

  float* resultp = (float*)d_out;            // (B,SQ,H)    = 4194304 f32
  float* attnp = resultp + 4194304;          // (NH*B,SQ,SK)= 33554432 f32

  cvt_kernel<<<dim3(2048), dim3(256), 0, stream>>>(memory, memB, 4194304);
  cvt_kernel<<<dim3(2048), dim3(256), 0, stream>>>(dec, decB, 4194304);
  cvt_kernel<<<dim3(128), dim3(256), 0, stream>>>(Wk, WkB, 262144);
  cvt_kernel<<<dim3(128), dim3(256), 0, stream>>>(Wv, WvB, 262144);
  cvt_kernel<<<dim3(128), dim3(256), 0, stream>>>(Wq, WqB, 262144);

  gemm_bt<0><<<dim3(64, 4), dim3(256), 0, stream>>>(decB, WqB, Qp);
  gemm_bt<0><<<dim3(64, 4), dim3(256), 0, stream>>>(memB, WkB, Kp);
  gemm_bt<1><<<dim3(64, 4), dim3(256), 0, stream>>>(memB, WvB, Vt);

  attn_pv_kernel<<<dim3(64, 4, 8), dim3(512), 0, stream>>>(Qp, Kp, Vt, mask, qmask,
                                                           attnp, outh);
  ln_kernel<<<dim3(2048), dim3(256), 0, stream>>>(outh, dec, gamma, beta, resultp);
}

// Round 3
// 220.082 us; speedup vs baseline: 1.6490x; 1.6490x over previous
//
#include <hip/hip_runtime.h>
#include <hip/hip_bf16.h>
#include <stdint.h>

#define NB 8
#define NSQ 1024
#define NSK 1024
#define NHID 512
#define NHEAD 4
#define NDH 128

typedef __attribute__((ext_vector_type(8))) short short8;
typedef __attribute__((ext_vector_type(4))) float f32x4;

__device__ __forceinline__ unsigned short f2b(float f) {
  unsigned int u = __builtin_bit_cast(unsigned int, f);
  u = u + 0x7FFFu + ((u >> 16) & 1u);
  return (unsigned short)(u >> 16);
}

// ---------------- K0: f32 -> bf16 convert (vectorized, 8 elems/thread) ----
__global__ void cvt_kernel(const float* __restrict__ src,
                           unsigned short* __restrict__ dst, int n) {
  int i = (blockIdx.x * blockDim.x + threadIdx.x) * 8;
  if (i >= n) return;
  float4 a = *(const float4*)(src + i);
  float4 b = *(const float4*)(src + i + 4);
  short8 o;
  o[0] = (short)f2b(a.x); o[1] = (short)f2b(a.y);
  o[2] = (short)f2b(a.z); o[3] = (short)f2b(a.w);
  o[4] = (short)f2b(b.x); o[5] = (short)f2b(b.y);
  o[6] = (short)f2b(b.z); o[7] = (short)f2b(b.w);
  *(short8*)(dst + i) = o;
}

// ---------------- K0b: pack mask int32 -> bitwords (bit j of word w = mask[w*32+j])
__global__ void pack_mask(const int* __restrict__ m, unsigned int* __restrict__ mw) {
  int w = blockIdx.x * blockDim.x + threadIdx.x;  // word index, 262144 total
  const int* src = m + (size_t)w * 32;
  unsigned int bits = 0;
#pragma unroll
  for (int j = 0; j < 32; j += 4) {
    int4 v = *(const int4*)(src + j);
    bits |= (v.x ? 1u << j : 0u) | (v.y ? 1u << (j + 1) : 0u) |
            (v.z ? 1u << (j + 2) : 0u) | (v.w ? 1u << (j + 3) : 0u);
  }
  mw[w] = bits;
}

// ---------------- K1: C[m,n] = sum_k A[m,k]*W[n,k]  (both bf16 row-major, K=512)
// MODE 0: C[m*512+n] bf16.  MODE 1: C transposed per-batch: C[((m>>10)*512+n)*1024 + (m&1023)]
template <int MODE>
__global__ __launch_bounds__(256) void gemm_bt(const unsigned short* __restrict__ A,
                                               const unsigned short* __restrict__ W,
                                               unsigned short* __restrict__ C) {
  __shared__ unsigned short tA[128 * 64];  // 128 rows x 64 k (128B rows, XOR-swizzled)
  __shared__ unsigned short tB[128 * 64];
  const int tid = threadIdx.x;
  const int lane = tid & 63;
  const int wave = tid >> 6;
  const int m0 = blockIdx.x * 128;
  const int n0 = blockIdx.y * 128;
  const int wm = (wave & 1) * 64;
  const int wn = (wave >> 1) * 64;
  const int r15 = lane & 15, hi = lane >> 4;

  f32x4 acc[4][4];
  for (int i = 0; i < 4; ++i)
    for (int j = 0; j < 4; ++j) acc[i][j] = (f32x4){0.f, 0.f, 0.f, 0.f};

  for (int kt = 0; kt < 8; ++kt) {
    const int k0 = kt * 64;
    for (int it = 0; it < 4; ++it) {
      int idx = it * 256 + tid;
      int row = idx >> 3, c = idx & 7;
      int cs = c ^ (row & 7);
      short8 va = *(const short8*)(A + (size_t)(m0 + row) * 512 + k0 + c * 8);
      *(short8*)&tA[row * 64 + cs * 8] = va;
      short8 vb = *(const short8*)(W + (size_t)(n0 + row) * 512 + k0 + c * 8);
      *(short8*)&tB[row * 64 + cs * 8] = vb;
    }
    __syncthreads();
    short8 af[2][4], bf[2][4];
    for (int kk = 0; kk < 2; ++kk) {
      for (int mi = 0; mi < 4; ++mi) {
        int row = wm + mi * 16 + r15;
        int ch = kk * 4 + hi;
        af[kk][mi] = *(short8*)&tA[row * 64 + (ch ^ (row & 7)) * 8];
      }
      for (int ni = 0; ni < 4; ++ni) {
        int row = wn + ni * 16 + r15;
        int ch = kk * 4 + hi;
        bf[kk][ni] = *(short8*)&tB[row * 64 + (ch ^ (row & 7)) * 8];
      }
      for (int mi = 0; mi < 4; ++mi)
        for (int ni = 0; ni < 4; ++ni)
          acc[mi][ni] = __builtin_amdgcn_mfma_f32_16x16x32_bf16(
              af[kk][mi], bf[kk][ni], acc[mi][ni], 0, 0, 0);
    }
    __syncthreads();
  }
  for (int mi = 0; mi < 4; ++mi) {
    for (int ni = 0; ni < 4; ++ni) {
      for (int r = 0; r < 4; ++r) {
        int m = m0 + wm + mi * 16 + hi * 4 + r;
        int n = n0 + wn + ni * 16 + r15;
        unsigned short v = f2b(acc[mi][ni][r]);
        if (MODE == 0) {
          C[(size_t)m * 512 + n] = v;
        } else {
          C[((size_t)(m >> 10) * 512 + n) * 1024 + (size_t)(m & 1023)] = v;
        }
      }
    }
  }
}

// ---------------- K2: fused scores+softmax+attn-write+PV -> outh (per-head f32)
// Waves: QK^T phase each wave owns a 128-wide k-slice; PV phase each wave owns
// a 16-wide d-slice and full k (no atomics, no cross-wave reduction).
__global__ __launch_bounds__(512) void attn_pv_kernel(
    const unsigned short* __restrict__ Qp, const unsigned short* __restrict__ Kp,
    const unsigned short* __restrict__ Vt, const unsigned int* __restrict__ maskw,
    const float* __restrict__ qmask, float* __restrict__ attn,
    float* __restrict__ outh) {
  __shared__ unsigned short tQ[16 * 128];    // 4KB, swizzled
  __shared__ unsigned short Plds[16 * 1024]; // 32KB bf16 P, swizzled
  __shared__ float redmax[16][8];
  __shared__ float redsum[16][8];
  const int qt = blockIdx.x, h = blockIdx.y, b = blockIdx.z;
  const int q0 = qt * 16;
  const int tid = threadIdx.x;
  const int lane = tid & 63, wave = tid >> 6;
  const int r15 = lane & 15, hi = lane >> 4;
  const int kbase = wave * 128;

  if (tid < 256) {
    int row = tid >> 4, c = tid & 15;
    short8 v = *(const short8*)(Qp + (size_t)(b * NSQ + q0 + row) * NHID + h * NDH + c * 8);
    int cs = c ^ (row & 7);
    *(short8*)&tQ[row * 128 + cs * 8] = v;
  }
  __syncthreads();

  short8 aq[4];
#pragma unroll
  for (int ks = 0; ks < 4; ++ks) {
    int ch = ks * 4 + hi;
    aq[ks] = *(short8*)&tQ[r15 * 128 + ((ch ^ (r15 & 7)) * 8)];
  }

  // ---- QK^T: wave owns k-columns [kbase, kbase+128) for all 16 q rows ----
  f32x4 acc[8];
#pragma unroll
  for (int f = 0; f < 8; ++f) acc[f] = (f32x4){0.f, 0.f, 0.f, 0.f};
  const unsigned short* kb = Kp + (size_t)b * NSK * NHID + h * NDH + hi * 8;
#pragma unroll
  for (int f = 0; f < 8; ++f) {
    const unsigned short* kptr = kb + (size_t)(kbase + f * 16 + r15) * NHID;
#pragma unroll
    for (int ks = 0; ks < 4; ++ks) {
      short8 bk = *(const short8*)(kptr + ks * 32);
      acc[f] = __builtin_amdgcn_mfma_f32_16x16x32_bf16(aq[ks], bk, acc[f], 0, 0, 0);
    }
  }

  // ---- mask (bit-packed) + scale; acc[f][r] is S[q=hi*4+r][k=kbase+f*16+r15]
  const float isd = 0.08838834764831845f;
  unsigned int mwa[4][4];  // [r][word]
#pragma unroll
  for (int r = 0; r < 4; ++r) {
    uint4 w4 = *(const uint4*)(maskw + ((size_t)(b * NSQ) + q0 + hi * 4 + r) * 32 +
                               (kbase >> 5));
    mwa[r][0] = w4.x; mwa[r][1] = w4.y; mwa[r][2] = w4.z; mwa[r][3] = w4.w;
  }
#pragma unroll
  for (int f = 0; f < 8; ++f)
#pragma unroll
    for (int r = 0; r < 4; ++r) {
      unsigned int bit = (mwa[r][f >> 1] >> ((f & 1) * 16 + r15)) & 1u;
      float s = acc[f][r] * isd;
      acc[f][r] = bit ? -4294967296.0f : s;
    }

  // ---- row max ----
  float M[4];
#pragma unroll
  for (int r = 0; r < 4; ++r) {
    float m = acc[0][r];
#pragma unroll
    for (int f = 1; f < 8; ++f) m = fmaxf(m, acc[f][r]);
    m = fmaxf(m, __shfl_xor(m, 1));
    m = fmaxf(m, __shfl_xor(m, 2));
    m = fmaxf(m, __shfl_xor(m, 4));
    m = fmaxf(m, __shfl_xor(m, 8));
    if (r15 == 0) redmax[hi * 4 + r][wave] = m;
  }
  __syncthreads();
#pragma unroll
  for (int r = 0; r < 4; ++r) {
    float4 a = *(float4*)&redmax[hi * 4 + r][0];
    float4 c = *(float4*)&redmax[hi * 4 + r][4];
    M[r] = fmaxf(fmaxf(fmaxf(a.x, a.y), fmaxf(a.z, a.w)),
                 fmaxf(fmaxf(c.x, c.y), fmaxf(c.z, c.w)));
  }

  // ---- exp + row sum ----
#pragma unroll
  for (int r = 0; r < 4; ++r) {
    float sm = 0.f;
#pragma unroll
    for (int f = 0; f < 8; ++f) {
      float e = __expf(acc[f][r] - M[r]);
      acc[f][r] = e;
      sm += e;
    }
    sm += __shfl_xor(sm, 1);
    sm += __shfl_xor(sm, 2);
    sm += __shfl_xor(sm, 4);
    sm += __shfl_xor(sm, 8);
    if (r15 == 0) redsum[hi * 4 + r][wave] = sm;
  }
  __syncthreads();
  float scl[4];
#pragma unroll
  for (int r = 0; r < 4; ++r) {
    float4 a = *(float4*)&redsum[hi * 4 + r][0];
    float4 c = *(float4*)&redsum[hi * 4 + r][4];
    float sum = (a.x + a.y + a.z + a.w) + (c.x + c.y + c.z + c.w);
    scl[r] = qmask[b * NSQ + q0 + hi * 4 + r] / sum;
  }

  // ---- write attn f32 + stage P bf16 into swizzled LDS ----
  float* abase = attn + ((size_t)(h * NB + b) * NSQ + q0 + hi * 4) * NSK + kbase + r15;
#pragma unroll
  for (int f = 0; f < 8; ++f)
#pragma unroll
    for (int r = 0; r < 4; ++r) {
      float p = acc[f][r] * scl[r];
      abase[(r << 10) + f * 16] = p;
      int q = hi * 4 + r;
      int k = kbase + f * 16 + r15;
      int cw = (k >> 3) ^ (q & 7);
      Plds[q * 1024 + cw * 8 + (k & 7)] = f2b(p);
    }
  __syncthreads();

  // ---- PV: wave owns d-slice [wave*16, wave*16+16), k = 0..1023 ----
  const int dw = wave * 16;
  f32x4 pacc0 = (f32x4){0.f, 0.f, 0.f, 0.f};
  f32x4 pacc1 = (f32x4){0.f, 0.f, 0.f, 0.f};
  const unsigned short* vrow =
      Vt + (size_t)(b * NHID + h * NDH + dw + r15) * NSK + hi * 8;
#pragma unroll
  for (int kc = 0; kc < 32; kc += 2) {
    short8 pa0 = *(short8*)&Plds[r15 * 1024 + ((((kc + 0) * 4 + hi) ^ (r15 & 7)) << 3)];
    short8 bv0 = *(const short8*)(vrow + (kc + 0) * 32);
    pacc0 = __builtin_amdgcn_mfma_f32_16x16x32_bf16(pa0, bv0, pacc0, 0, 0, 0);
    short8 pa1 = *(short8*)&Plds[r15 * 1024 + ((((kc + 1) * 4 + hi) ^ (r15 & 7)) << 3)];
    short8 bv1 = *(const short8*)(vrow + (kc + 1) * 32);
    pacc1 = __builtin_amdgcn_mfma_f32_16x16x32_bf16(pa1, bv1, pacc1, 0, 0, 0);
  }
  f32x4 pacc = pacc0 + pacc1;
#pragma unroll
  for (int r = 0; r < 4; ++r) {
    outh[((size_t)(b * NSQ) + q0 + hi * 4 + r) * NHID + h * NDH + dw + r15] = pacc[r];
  }
}

// ---------------- K3: residual + LayerNorm: result = LN(outh + dec) ----------
__global__ __launch_bounds__(256) void ln_kernel(const float* __restrict__ outh,
                                                 const float* __restrict__ dec,
                                                 const float* __restrict__ gamma,
                                                 const float* __restrict__ beta,
                                                 float* __restrict__ result) {
  const int tid = threadIdx.x;
  const int lane = tid & 63, wave = tid >> 6;
  const size_t row = (size_t)blockIdx.x * 4 + wave;
  const float* xr = outh + row * NHID;
  const float* dr = dec + row * NHID;
  float v[8];
  float s = 0.f;
  for (int j = 0; j < 2; ++j) {
    float4 a = *(const float4*)(xr + lane * 8 + j * 4);
    float4 d = *(const float4*)(dr + lane * 8 + j * 4);
    v[j * 4 + 0] = a.x + d.x; v[j * 4 + 1] = a.y + d.y;
    v[j * 4 + 2] = a.z + d.z; v[j * 4 + 3] = a.w + d.w;
  }
  for (int j = 0; j < 8; ++j) s += v[j];
  for (int off = 32; off > 0; off >>= 1) s += __shfl_xor(s, off);
  float mu = s * (1.f / 512.f);
  float s2 = 0.f;
  for (int j = 0; j < 8; ++j) {
    float d = v[j] - mu;
    s2 += d * d;
  }
  for (int off = 32; off > 0; off >>= 1) s2 += __shfl_xor(s2, off);
  float rstd = rsqrtf(s2 * (1.f / 512.f) + 1e-5f);
  float* out = result + row * NHID;
  for (int j = 0; j < 2; ++j) {
    float4 g = *(const float4*)(gamma + lane * 8 + j * 4);
    float4 bt = *(const float4*)(beta + lane * 8 + j * 4);
    float4 o;
    o.x = (v[j * 4 + 0] - mu) * rstd * g.x + bt.x;
    o.y = (v[j * 4 + 1] - mu) * rstd * g.y + bt.y;
    o.z = (v[j * 4 + 2] - mu) * rstd * g.z + bt.z;
    o.w = (v[j * 4 + 3] - mu) * rstd * g.w + bt.w;
    *(float4*)(out + lane * 8 + j * 4) = o;
  }
}

extern "C" void kernel_launch(void* const* d_in, const int* in_sizes, int n_in,
                              void* d_out, int out_size, void* d_ws, size_t ws_size,
                              hipStream_t stream) {
  const float* memory = (const float*)d_in[0];
  const float* dec = (const float*)d_in[1];
  const int* mask = (const int*)d_in[2];
  const float* qmask = (const float*)d_in[3];
  const float* Wk = (const float*)d_in[4];
  const float* Wv = (const float*)d_in[5];
  const float* Wq = (const float*)d_in[6];
  const float* gamma = (const float*)d_in[7];
  const float* beta = (const float*)d_in[8];

  char* ws = (char*)d_ws;
  unsigned short* memB = (unsigned short*)(ws + 0);         // 8  MB
  unsigned short* decB = (unsigned short*)(ws + 8388608);   // 8  MB
  unsigned short* WkB = (unsigned short*)(ws + 16777216);   // .5 MB
  unsigned short* WvB = (unsigned short*)(ws + 17301504);   // .5 MB
  unsigned short* WqB = (unsigned short*)(ws + 17825792);   // .5 MB
  unsigned short* Kp = (unsigned short*)(ws + 18350080);    // 8  MB  [b,s,o]
  unsigned short* Qp = (unsigned short*)(ws + 26738688);    // 8  MB  [b,s,o]
  unsigned short* Vt = (unsigned short*)(ws + 35127296);    // 8  MB  [b,o,s]
  unsigned int* maskw = (unsigned int*)(ws + 43515904);     // 1  MB
  float* outh = (float*)(ws + 0);  // 16 MB, overlays memB/decB (dead after gemms)

  float* resultp = (float*)d_out;            // (B,SQ,H)    = 4194304 f32
  float* attnp = resultp + 4194304;          // (NH*B,SQ,SK)= 33554432 f32

  cvt_kernel<<<dim3(2048), dim3(256), 0, stream>>>(memory, memB, 4194304);
  cvt_kernel<<<dim3(2048), dim3(256), 0, stream>>>(dec, decB, 4194304);
  cvt_kernel<<<dim3(128), dim3(256), 0, stream>>>(Wk, WkB, 262144);
  cvt_kernel<<<dim3(128), dim3(256), 0, stream>>>(Wv, WvB, 262144);
  cvt_kernel<<<dim3(128), dim3(256), 0, stream>>>(Wq, WqB, 262144);
  pack_mask<<<dim3(1024), dim3(256), 0, stream>>>(mask, maskw);

  gemm_bt<0><<<dim3(64, 4), dim3(256), 0, stream>>>(decB, WqB, Qp);
  gemm_bt<0><<<dim3(64, 4), dim3(256), 0, stream>>>(memB, WkB, Kp);
  gemm_bt<1><<<dim3(64, 4), dim3(256), 0, stream>>>(memB, WvB, Vt);

  attn_pv_kernel<<<dim3(64, 4, 8), dim3(512), 0, stream>>>(Qp, Kp, Vt, maskw, qmask,
                                                           attnp, outh);
  ln_kernel<<<dim3(2048), dim3(256), 0, stream>>>(outh, dec, gamma, beta, resultp);
}

// Round 4
// 196.869 us; speedup vs baseline: 1.8435x; 1.1179x over previous
//
#include <hip/hip_runtime.h>
#include <hip/hip_bf16.h>
#include <stdint.h>

#define NB 8
#define NSQ 1024
#define NSK 1024
#define NHID 512
#define NHEAD 4
#define NDH 128

typedef __attribute__((ext_vector_type(8))) short short8;
typedef __attribute__((ext_vector_type(4))) float f32x4;

__device__ __forceinline__ unsigned short f2b(float f) {
  unsigned int u = __builtin_bit_cast(unsigned int, f);
  u = u + 0x7FFFu + ((u >> 16) & 1u);
  return (unsigned short)(u >> 16);
}

__device__ __forceinline__ short8 pack8(float4 a, float4 b) {
  short8 o;
  o[0] = (short)f2b(a.x); o[1] = (short)f2b(a.y);
  o[2] = (short)f2b(a.z); o[3] = (short)f2b(a.w);
  o[4] = (short)f2b(b.x); o[5] = (short)f2b(b.y);
  o[6] = (short)f2b(b.z); o[7] = (short)f2b(b.w);
  return o;
}

// ---------------- K0b: pack mask int32 -> bitwords (bit j of word w = mask[w*32+j])
__global__ void pack_mask(const int* __restrict__ m, unsigned int* __restrict__ mw) {
  int w = blockIdx.x * blockDim.x + threadIdx.x;  // word index, 262144 total
  const int* src = m + (size_t)w * 32;
  unsigned int bits = 0;
#pragma unroll
  for (int j = 0; j < 32; j += 4) {
    int4 v = *(const int4*)(src + j);
    bits |= (v.x ? 1u << j : 0u) | (v.y ? 1u << (j + 1) : 0u) |
            (v.z ? 1u << (j + 2) : 0u) | (v.w ? 1u << (j + 3) : 0u);
  }
  mw[w] = bits;
}

// ---------------- K1: C[m,n] = sum_k A[m,k]*W[n,k]; A,W are f32 row-major (K=512),
// converted to bf16 during LDS staging. C bf16.
// MODE 0: C[m*512+n].  MODE 1: C transposed per-batch: C[((m>>10)*512+n)*1024 + (m&1023)]
template <int MODE>
__global__ __launch_bounds__(256) void gemm_bt(const float* __restrict__ A,
                                               const float* __restrict__ W,
                                               unsigned short* __restrict__ C) {
  __shared__ unsigned short tA[128 * 64];  // 128 rows x 64 k, XOR-swizzled
  __shared__ unsigned short tB[128 * 64];
  const int tid = threadIdx.x;
  const int lane = tid & 63;
  const int wave = tid >> 6;
  const int m0 = blockIdx.x * 128;
  const int n0 = blockIdx.y * 128;
  const int wm = (wave & 1) * 64;
  const int wn = (wave >> 1) * 64;
  const int r15 = lane & 15, hi = lane >> 4;

  f32x4 acc[4][4];
  for (int i = 0; i < 4; ++i)
    for (int j = 0; j < 4; ++j) acc[i][j] = (f32x4){0.f, 0.f, 0.f, 0.f};

  for (int kt = 0; kt < 8; ++kt) {
    const int k0 = kt * 64;
    for (int it = 0; it < 4; ++it) {
      int idx = it * 256 + tid;
      int row = idx >> 3, c = idx & 7;
      int cs = c ^ (row & 7);
      const float* sa = A + (size_t)(m0 + row) * 512 + k0 + c * 8;
      float4 a0 = *(const float4*)sa;
      float4 a1 = *(const float4*)(sa + 4);
      *(short8*)&tA[row * 64 + cs * 8] = pack8(a0, a1);
      const float* sw = W + (size_t)(n0 + row) * 512 + k0 + c * 8;
      float4 b0 = *(const float4*)sw;
      float4 b1 = *(const float4*)(sw + 4);
      *(short8*)&tB[row * 64 + cs * 8] = pack8(b0, b1);
    }
    __syncthreads();
    short8 af[2][4], bf[2][4];
    for (int kk = 0; kk < 2; ++kk) {
      for (int mi = 0; mi < 4; ++mi) {
        int row = wm + mi * 16 + r15;
        int ch = kk * 4 + hi;
        af[kk][mi] = *(short8*)&tA[row * 64 + (ch ^ (row & 7)) * 8];
      }
      for (int ni = 0; ni < 4; ++ni) {
        int row = wn + ni * 16 + r15;
        int ch = kk * 4 + hi;
        bf[kk][ni] = *(short8*)&tB[row * 64 + (ch ^ (row & 7)) * 8];
      }
      for (int mi = 0; mi < 4; ++mi)
        for (int ni = 0; ni < 4; ++ni)
          acc[mi][ni] = __builtin_amdgcn_mfma_f32_16x16x32_bf16(
              af[kk][mi], bf[kk][ni], acc[mi][ni], 0, 0, 0);
    }
    __syncthreads();
  }
  for (int mi = 0; mi < 4; ++mi) {
    for (int ni = 0; ni < 4; ++ni) {
      for (int r = 0; r < 4; ++r) {
        int m = m0 + wm + mi * 16 + hi * 4 + r;
        int n = n0 + wn + ni * 16 + r15;
        unsigned short v = f2b(acc[mi][ni][r]);
        if (MODE == 0) {
          C[(size_t)m * 512 + n] = v;
        } else {
          C[((size_t)(m >> 10) * 512 + n) * 1024 + (size_t)(m & 1023)] = v;
        }
      }
    }
  }
}

// ---------------- K2: fused scores+softmax+attn-write+PV, QBLK=32 ----
// QK^T phase: wave owns k-slice [wave*128, wave*128+128) for 32 q rows (2 frags).
// PV phase: wave owns d-slice [wave*16, ..+16) for 32 q rows, full k.
__global__ __launch_bounds__(512) void attn_pv_kernel(
    const unsigned short* __restrict__ Qp, const unsigned short* __restrict__ Kp,
    const unsigned short* __restrict__ Vt, const unsigned int* __restrict__ maskw,
    const float* __restrict__ qmask, float* __restrict__ attn,
    float* __restrict__ outh) {
  __shared__ unsigned short tQ[32 * 128];    // 8KB, swizzled
  __shared__ unsigned short Plds[32 * 1024]; // 64KB bf16 P, swizzled
  __shared__ float redmax[32][8];
  __shared__ float redsum[32][8];
  const int qt = blockIdx.x, h = blockIdx.y, b = blockIdx.z;
  const int q0 = qt * 32;
  const int tid = threadIdx.x;
  const int lane = tid & 63, wave = tid >> 6;
  const int r15 = lane & 15, hi = lane >> 4;
  const int kbase = wave * 128;

  {
    int row = tid >> 4, c = tid & 15;
    short8 v = *(const short8*)(Qp + (size_t)(b * NSQ + q0 + row) * NHID + h * NDH + c * 8);
    int cs = c ^ (row & 7);
    *(short8*)&tQ[row * 128 + cs * 8] = v;
  }
  __syncthreads();

  short8 aq[2][4];
#pragma unroll
  for (int g = 0; g < 2; ++g)
#pragma unroll
    for (int ks = 0; ks < 4; ++ks) {
      int ch = ks * 4 + hi;
      aq[g][ks] = *(short8*)&tQ[(g * 16 + r15) * 128 + ((ch ^ (r15 & 7)) * 8)];
    }

  // ---- QK^T ----
  f32x4 acc[2][8];
#pragma unroll
  for (int g = 0; g < 2; ++g)
#pragma unroll
    for (int f = 0; f < 8; ++f) acc[g][f] = (f32x4){0.f, 0.f, 0.f, 0.f};
  const unsigned short* kb = Kp + (size_t)b * NSK * NHID + h * NDH + hi * 8;
  __builtin_amdgcn_s_setprio(1);
#pragma unroll
  for (int f = 0; f < 8; ++f) {
    const unsigned short* kptr = kb + (size_t)(kbase + f * 16 + r15) * NHID;
    short8 bk[4];
#pragma unroll
    for (int ks = 0; ks < 4; ++ks) bk[ks] = *(const short8*)(kptr + ks * 32);
#pragma unroll
    for (int ks = 0; ks < 4; ++ks) {
      acc[0][f] = __builtin_amdgcn_mfma_f32_16x16x32_bf16(aq[0][ks], bk[ks], acc[0][f], 0, 0, 0);
      acc[1][f] = __builtin_amdgcn_mfma_f32_16x16x32_bf16(aq[1][ks], bk[ks], acc[1][f], 0, 0, 0);
    }
  }
  __builtin_amdgcn_s_setprio(0);

  // ---- mask + scale; acc[g][f][r] is S[q=g*16+hi*4+r][k=kbase+f*16+r15] ----
  const float isd = 0.08838834764831845f;
#pragma unroll
  for (int g = 0; g < 2; ++g) {
    unsigned int mwa[4][4];
#pragma unroll
    for (int r = 0; r < 4; ++r) {
      uint4 w4 = *(const uint4*)(maskw +
          ((size_t)(b * NSQ) + q0 + g * 16 + hi * 4 + r) * 32 + (kbase >> 5));
      mwa[r][0] = w4.x; mwa[r][1] = w4.y; mwa[r][2] = w4.z; mwa[r][3] = w4.w;
    }
#pragma unroll
    for (int f = 0; f < 8; ++f)
#pragma unroll
      for (int r = 0; r < 4; ++r) {
        unsigned int bit = (mwa[r][f >> 1] >> ((f & 1) * 16 + r15)) & 1u;
        float s = acc[g][f][r] * isd;
        acc[g][f][r] = bit ? -4294967296.0f : s;
      }
  }

  // ---- row max ----
  float M[2][4];
#pragma unroll
  for (int g = 0; g < 2; ++g)
#pragma unroll
    for (int r = 0; r < 4; ++r) {
      float m = acc[g][0][r];
#pragma unroll
      for (int f = 1; f < 8; ++f) m = fmaxf(m, acc[g][f][r]);
      m = fmaxf(m, __shfl_xor(m, 1));
      m = fmaxf(m, __shfl_xor(m, 2));
      m = fmaxf(m, __shfl_xor(m, 4));
      m = fmaxf(m, __shfl_xor(m, 8));
      if (r15 == 0) redmax[g * 16 + hi * 4 + r][wave] = m;
    }
  __syncthreads();
#pragma unroll
  for (int g = 0; g < 2; ++g)
#pragma unroll
    for (int r = 0; r < 4; ++r) {
      float4 a = *(float4*)&redmax[g * 16 + hi * 4 + r][0];
      float4 c = *(float4*)&redmax[g * 16 + hi * 4 + r][4];
      M[g][r] = fmaxf(fmaxf(fmaxf(a.x, a.y), fmaxf(a.z, a.w)),
                      fmaxf(fmaxf(c.x, c.y), fmaxf(c.z, c.w)));
    }

  // ---- exp + row sum ----
#pragma unroll
  for (int g = 0; g < 2; ++g)
#pragma unroll
    for (int r = 0; r < 4; ++r) {
      float sm = 0.f;
#pragma unroll
      for (int f = 0; f < 8; ++f) {
        float e = __expf(acc[g][f][r] - M[g][r]);
        acc[g][f][r] = e;
        sm += e;
      }
      sm += __shfl_xor(sm, 1);
      sm += __shfl_xor(sm, 2);
      sm += __shfl_xor(sm, 4);
      sm += __shfl_xor(sm, 8);
      if (r15 == 0) redsum[g * 16 + hi * 4 + r][wave] = sm;
    }
  __syncthreads();
  float scl[2][4];
#pragma unroll
  for (int g = 0; g < 2; ++g)
#pragma unroll
    for (int r = 0; r < 4; ++r) {
      float4 a = *(float4*)&redsum[g * 16 + hi * 4 + r][0];
      float4 c = *(float4*)&redsum[g * 16 + hi * 4 + r][4];
      float sum = (a.x + a.y + a.z + a.w) + (c.x + c.y + c.z + c.w);
      scl[g][r] = qmask[b * NSQ + q0 + g * 16 + hi * 4 + r] / sum;
    }

  // ---- write attn f32 + stage P bf16 into swizzled LDS ----
#pragma unroll
  for (int g = 0; g < 2; ++g) {
    float* abase =
        attn + ((size_t)(h * NB + b) * NSQ + q0 + g * 16 + hi * 4) * NSK + kbase + r15;
#pragma unroll
    for (int f = 0; f < 8; ++f)
#pragma unroll
      for (int r = 0; r < 4; ++r) {
        float p = acc[g][f][r] * scl[g][r];
        abase[(r << 10) + f * 16] = p;
        int q = g * 16 + hi * 4 + r;
        int k = kbase + f * 16 + r15;
        int cw = (k >> 3) ^ (q & 7);
        Plds[q * 1024 + cw * 8 + (k & 7)] = f2b(p);
      }
  }
  __syncthreads();

  // ---- PV: wave owns d-slice [wave*16, +16), 32 q rows, k = 0..1023 ----
  const int dw = wave * 16;
  f32x4 p0e = (f32x4){0.f, 0.f, 0.f, 0.f}, p0o = p0e, p1e = p0e, p1o = p0e;
  const unsigned short* vrow =
      Vt + (size_t)(b * NHID + h * NDH + dw + r15) * NSK + hi * 8;
  __builtin_amdgcn_s_setprio(1);
#pragma unroll
  for (int kc = 0; kc < 32; kc += 2) {
    short8 bv0 = *(const short8*)(vrow + (kc + 0) * 32);
    short8 bv1 = *(const short8*)(vrow + (kc + 1) * 32);
    short8 a00 = *(short8*)&Plds[(r15) * 1024 + ((((kc + 0) * 4 + hi) ^ (r15 & 7)) << 3)];
    short8 a10 = *(short8*)&Plds[(16 + r15) * 1024 + ((((kc + 0) * 4 + hi) ^ (r15 & 7)) << 3)];
    short8 a01 = *(short8*)&Plds[(r15) * 1024 + ((((kc + 1) * 4 + hi) ^ (r15 & 7)) << 3)];
    short8 a11 = *(short8*)&Plds[(16 + r15) * 1024 + ((((kc + 1) * 4 + hi) ^ (r15 & 7)) << 3)];
    p0e = __builtin_amdgcn_mfma_f32_16x16x32_bf16(a00, bv0, p0e, 0, 0, 0);
    p1e = __builtin_amdgcn_mfma_f32_16x16x32_bf16(a10, bv0, p1e, 0, 0, 0);
    p0o = __builtin_amdgcn_mfma_f32_16x16x32_bf16(a01, bv1, p0o, 0, 0, 0);
    p1o = __builtin_amdgcn_mfma_f32_16x16x32_bf16(a11, bv1, p1o, 0, 0, 0);
  }
  __builtin_amdgcn_s_setprio(0);
  f32x4 pa0 = p0e + p0o;
  f32x4 pa1 = p1e + p1o;
#pragma unroll
  for (int r = 0; r < 4; ++r) {
    outh[((size_t)(b * NSQ) + q0 + hi * 4 + r) * NHID + h * NDH + dw + r15] = pa0[r];
    outh[((size_t)(b * NSQ) + q0 + 16 + hi * 4 + r) * NHID + h * NDH + dw + r15] = pa1[r];
  }
}

// ---------------- K3: residual + LayerNorm: result = LN(outh + dec) ----------
__global__ __launch_bounds__(256) void ln_kernel(const float* __restrict__ outh,
                                                 const float* __restrict__ dec,
                                                 const float* __restrict__ gamma,
                                                 const float* __restrict__ beta,
                                                 float* __restrict__ result) {
  const int tid = threadIdx.x;
  const int lane = tid & 63, wave = tid >> 6;
  const size_t row = (size_t)blockIdx.x * 4 + wave;
  const float* xr = outh + row * NHID;
  const float* dr = dec + row * NHID;
  float v[8];
  float s = 0.f;
  for (int j = 0; j < 2; ++j) {
    float4 a = *(const float4*)(xr + lane * 8 + j * 4);
    float4 d = *(const float4*)(dr + lane * 8 + j * 4);
    v[j * 4 + 0] = a.x + d.x; v[j * 4 + 1] = a.y + d.y;
    v[j * 4 + 2] = a.z + d.z; v[j * 4 + 3] = a.w + d.w;
  }
  for (int j = 0; j < 8; ++j) s += v[j];
  for (int off = 32; off > 0; off >>= 1) s += __shfl_xor(s, off);
  float mu = s * (1.f / 512.f);
  float s2 = 0.f;
  for (int j = 0; j < 8; ++j) {
    float d = v[j] - mu;
    s2 += d * d;
  }
  for (int off = 32; off > 0; off >>= 1) s2 += __shfl_xor(s2, off);
  float rstd = rsqrtf(s2 * (1.f / 512.f) + 1e-5f);
  float* out = result + row * NHID;
  for (int j = 0; j < 2; ++j) {
    float4 g = *(const float4*)(gamma + lane * 8 + j * 4);
    float4 bt = *(const float4*)(beta + lane * 8 + j * 4);
    float4 o;
    o.x = (v[j * 4 + 0] - mu) * rstd * g.x + bt.x;
    o.y = (v[j * 4 + 1] - mu) * rstd * g.y + bt.y;
    o.z = (v[j * 4 + 2] - mu) * rstd * g.z + bt.z;
    o.w = (v[j * 4 + 3] - mu) * rstd * g.w + bt.w;
    *(float4*)(out + lane * 8 + j * 4) = o;
  }
}

extern "C" void kernel_launch(void* const* d_in, const int* in_sizes, int n_in,
                              void* d_out, int out_size, void* d_ws, size_t ws_size,
                              hipStream_t stream) {
  const float* memory = (const float*)d_in[0];
  const float* dec = (const float*)d_in[1];
  const int* mask = (const int*)d_in[2];
  const float* qmask = (const float*)d_in[3];
  const float* Wk = (const float*)d_in[4];
  const float* Wv = (const float*)d_in[5];
  const float* Wq = (const float*)d_in[6];
  const float* gamma = (const float*)d_in[7];
  const float* beta = (const float*)d_in[8];

  char* ws = (char*)d_ws;
  float* outh = (float*)(ws + 0);                          // 16 MB
  unsigned short* Kp = (unsigned short*)(ws + 16777216);   // 8 MB  [b,s,o]
  unsigned short* Qp = (unsigned short*)(ws + 25165824);   // 8 MB  [b,s,o]
  unsigned short* Vt = (unsigned short*)(ws + 33554432);   // 8 MB  [b,o,s]
  unsigned int* maskw = (unsigned int*)(ws + 41943040);    // 1 MB

  float* resultp = (float*)d_out;            // (B,SQ,H)    = 4194304 f32
  float* attnp = resultp + 4194304;          // (NH*B,SQ,SK)= 33554432 f32

  pack_mask<<<dim3(1024), dim3(256), 0, stream>>>(mask, maskw);
  gemm_bt<0><<<dim3(64, 4), dim3(256), 0, stream>>>(dec, Wq, Qp);
  gemm_bt<0><<<dim3(64, 4), dim3(256), 0, stream>>>(memory, Wk, Kp);
  gemm_bt<1><<<dim3(64, 4), dim3(256), 0, stream>>>(memory, Wv, Vt);

  attn_pv_kernel<<<dim3(32, 4, 8), dim3(512), 0, stream>>>(Qp, Kp, Vt, maskw, qmask,
                                                           attnp, outh);
  ln_kernel<<<dim3(2048), dim3(256), 0, stream>>>(outh, dec, gamma, beta, resultp);
}